// Round 1
// baseline (817.755 us; speedup 1.0000x reference)
//
#include <hip/hip_runtime.h>
#include <hip/hip_bf16.h>
#include <math.h>

#define HIDDEN 2048
#define SEQ    2048
#define NH     16
#define NKV    2
#define HD     128

typedef __attribute__((ext_vector_type(8))) short s16x8;
typedef __attribute__((ext_vector_type(4))) short s16x4;
typedef __attribute__((ext_vector_type(4))) float f32x4;

__device__ __forceinline__ unsigned short f2bf(float f) {
  union { float f; unsigned int u; } v; v.f = f;
  unsigned int u = v.u;
  u += 0x7FFFu + ((u >> 16) & 1u);
  return (unsigned short)(u >> 16);
}

__device__ __forceinline__ s16x4 cvt4(float4 f) {
  s16x4 r;
  r.x = (short)f2bf(f.x); r.y = (short)f2bf(f.y);
  r.z = (short)f2bf(f.z); r.w = (short)f2bf(f.w);
  return r;
}

__device__ __forceinline__ f32x4 mfma16(s16x8 a, s16x8 b, f32x4 c) {
  return __builtin_amdgcn_mfma_f32_16x16x32_bf16(a, b, c, 0, 0, 0);
}

// ---------------------------------------------------------------------------
// Kernel 1: QKV projection + RoPE (Q,K) / transpose-store (V).  (unchanged)
// ---------------------------------------------------------------------------
__global__ void __launch_bounds__(256)
qkv_rope_kernel(const float* __restrict__ q_hidden,
                const float* __restrict__ k_hidden,
                const float* __restrict__ v_hidden,
                const float* __restrict__ q_w,
                const float* __restrict__ k_w,
                const float* __restrict__ v_w,
                const int* __restrict__ pos_ids,
                unsigned short* __restrict__ Qb,   // [16][2048][128] bf16
                unsigned short* __restrict__ Kb,   // [2][2048][128]  bf16
                unsigned short* __restrict__ Vtb)  // [2][128][2048]  bf16
{
  const int mt  = blockIdx.x;   // 0..15  (row tile)
  const int bid = blockIdx.y;   // 0..19  (16 Q, 2 K, 2 V)

  const float* A;
  const float* B;
  int mode, head;
  if (bid < 16)      { mode = 0; head = bid;      A = q_hidden + (size_t)head*SEQ*HIDDEN; B = q_w + (size_t)head*HD*HIDDEN; }
  else if (bid < 18) { mode = 1; head = bid - 16; A = k_hidden + (size_t)head*SEQ*HIDDEN; B = k_w + (size_t)head*HD*HIDDEN; }
  else               { mode = 2; head = bid - 18; A = v_hidden + (size_t)head*SEQ*HIDDEN; B = v_w + (size_t)head*HD*HIDDEN; }

  __shared__ __align__(16) unsigned short Asm[128 * 40];
  __shared__ __align__(16) unsigned short Bsm[128 * 40];

  const int tid  = threadIdx.x;
  const int w    = tid >> 6;
  const int lane = tid & 63;
  const int quad = lane >> 4;
  const int col  = lane & 15;
  const int srow = tid >> 3;
  const int schk = tid & 7;

  f32x4 acc[2][8];
  #pragma unroll
  for (int i = 0; i < 2; i++)
    #pragma unroll
    for (int j = 0; j < 8; j++)
      acc[i][j] = (f32x4){0.f, 0.f, 0.f, 0.f};

  const int row0 = mt * 128;

  for (int k0 = 0; k0 < HIDDEN; k0 += 32) {
    #pragma unroll
    for (int p = 0; p < 4; p++) {
      int r = srow + p * 32;
      float4 va = *(const float4*)(A + (size_t)(row0 + r) * HIDDEN + k0 + schk * 4);
      float4 vb = *(const float4*)(B + (size_t)r * HIDDEN + k0 + schk * 4);
      *(s16x4*)&Asm[r * 40 + schk * 4] = cvt4(va);
      *(s16x4*)&Bsm[r * 40 + schk * 4] = cvt4(vb);
    }
    __syncthreads();
    s16x8 af0 = *(const s16x8*)&Asm[(w * 32 + col) * 40 + quad * 8];
    s16x8 af1 = *(const s16x8*)&Asm[(w * 32 + 16 + col) * 40 + quad * 8];
    #pragma unroll
    for (int j = 0; j < 8; j++) {
      s16x8 bf = *(const s16x8*)&Bsm[(j * 16 + col) * 40 + quad * 8];
      acc[0][j] = mfma16(af0, bf, acc[0][j]);
      acc[1][j] = mfma16(af1, bf, acc[1][j]);
    }
    __syncthreads();
  }

  if (mode < 2) {
    unsigned short* Cb = (mode == 0) ? (Qb + (size_t)head * SEQ * HD)
                                     : (Kb + (size_t)head * SEQ * HD);
    const float scl = (mode == 0) ? 0.08838834764831845f : 1.0f;
    float invf[4];
    #pragma unroll
    for (int j = 0; j < 4; j++)
      invf[j] = __powf(1000000.0f, -(float)(j * 16 + col) * (1.0f / 64.0f));
    #pragma unroll
    for (int i = 0; i < 2; i++) {
      #pragma unroll
      for (int r = 0; r < 4; r++) {
        int l = row0 + w * 32 + i * 16 + quad * 4 + r;
        float p = (float)pos_ids[l];
        unsigned short* crow = Cb + (size_t)l * HD;
        #pragma unroll
        for (int j = 0; j < 4; j++) {
          float ss, cc;
          sincosf(p * invf[j], &ss, &cc);
          float x1 = acc[i][j][r];
          float x2 = acc[i][j + 4][r];
          crow[j * 16 + col]       = f2bf((x1 * cc - x2 * ss) * scl);
          crow[(j + 4) * 16 + col] = f2bf((x2 * cc + x1 * ss) * scl);
        }
      }
    }
  } else {
    unsigned short* Cb = Vtb + (size_t)head * HD * SEQ;
    #pragma unroll
    for (int i = 0; i < 2; i++)
      #pragma unroll
      for (int r = 0; r < 4; r++) {
        int l = row0 + w * 32 + i * 16 + quad * 4 + r;
        #pragma unroll
        for (int j = 0; j < 8; j++) {
          int h = j * 16 + col;
          Cb[(size_t)h * SEQ + l] = f2bf(acc[i][j][r]);
        }
      }
  }
}

// ---------------------------------------------------------------------------
// Kernel 2: flash attention (causal, GQA) — restructured for occupancy.
//  - 64-row q tiles -> grid (32,16)=512 blocks; 4 waves x 16 q-rows each.
//  - __launch_bounds__(256,2) caps VGPR at 128 so 2 blocks/CU co-reside
//    (2 waves/SIMD; previous version had 1 wave/SIMD -> pure latency bound).
//  - swapped QK^T: mfma(K,Q) puts a full q-row's S values in one lane
//    (plus its 3 quad-mates) -> softmax is in-lane tree + 2 xor-shuffles,
//    replacing 64 ds_bpermute/iter/thread.
//  - P bounce through a per-WAVE LDS buffer: no __syncthreads in the loop,
//    only lgkmcnt(0) (wave-private ordering).
//  - LPT: qt = 31 - blockIdx.x dispatches heavy causal tiles first.
// ---------------------------------------------------------------------------
__global__ void __launch_bounds__(256, 2)
attn_kernel(const unsigned short* __restrict__ Qb,
            const unsigned short* __restrict__ Kb,
            const unsigned short* __restrict__ Vtb,
            unsigned short* __restrict__ Ob)   // [16][2048][128] bf16
{
  const int qt = 31 - (int)blockIdx.x;  // heavy tiles dispatch first (LPT)
  const int n  = blockIdx.y;            // head 0..15
  const int kv = n >> 3;

  const int tid  = threadIdx.x;
  const int w    = tid >> 6;
  const int lane = tid & 63;
  const int quad = lane >> 4;
  const int col  = lane & 15;

  // per-wave P buffer: 16 q-rows x 128 s, stride 136 (272B: 8B-aligned writes,
  // both b64 writes and b128 reads sit at the LDS-BW floor, no extra conflicts)
  __shared__ __align__(16) unsigned short Psm[4][16 * 136];
  unsigned short* Pw = &Psm[w][0];

  const unsigned short* Qh = Qb  + (size_t)n  * SEQ * HD;
  const unsigned short* Kh = Kb  + (size_t)kv * SEQ * HD;
  const unsigned short* Vh = Vtb + (size_t)kv * HD * SEQ;

  // this lane's q row (swapped layout: q is the MFMA n-index = lane&15)
  const int qrow = qt * 64 + w * 16 + col;

  // Q fragment (B-operand: lane&15 = q row, quad = k-chunk)
  s16x8 qfrag[4];
  #pragma unroll
  for (int kk = 0; kk < 4; kk++)
    qfrag[kk] = *(const s16x8*)(Qh + (size_t)qrow * HD + kk * 32 + quad * 8);

  f32x4 oacc[8];
  #pragma unroll
  for (int j = 0; j < 8; j++) oacc[j] = (f32x4){0.f, 0.f, 0.f, 0.f};
  float m_run = -3e38f, l_run = 0.f;

  const int nst = (qt >> 1) + 1;   // 128-row kv tiles needed for 64 q rows

  for (int st = 0; st < nst; st++) {
    // ---- S^T = K @ Q^T : sc[j][r] = S[s = st*128+j*16+quad*4+r][q = qrow]
    f32x4 sc[8];
    #pragma unroll
    for (int j = 0; j < 8; j++) sc[j] = (f32x4){0.f, 0.f, 0.f, 0.f};
    #pragma unroll
    for (int kk = 0; kk < 4; kk++) {
      #pragma unroll
      for (int j = 0; j < 8; j++) {
        s16x8 kf = *(const s16x8*)(Kh + (size_t)(st * 128 + j * 16 + col) * HD + kk * 32 + quad * 8);
        sc[j] = mfma16(kf, qfrag[kk], sc[j]);
      }
    }

    // ---- causal mask (only the diagonal tile can violate s <= q)
    if (st == nst - 1) {
      #pragma unroll
      for (int j = 0; j < 8; j++)
        #pragma unroll
        for (int r = 0; r < 4; r++) {
          int sg = st * 128 + j * 16 + quad * 4 + r;
          if (sg > qrow) sc[j][r] = -1e30f;
        }
    }

    // ---- online softmax: in-lane tree over 32 vals + 2 xor-shuffles
    float mj[8];
    #pragma unroll
    for (int j = 0; j < 8; j++)
      mj[j] = fmaxf(fmaxf(sc[j][0], sc[j][1]), fmaxf(sc[j][2], sc[j][3]));
    float mx = fmaxf(fmaxf(fmaxf(mj[0], mj[1]), fmaxf(mj[2], mj[3])),
                     fmaxf(fmaxf(mj[4], mj[5]), fmaxf(mj[6], mj[7])));
    mx = fmaxf(mx, __shfl_xor(mx, 16, 64));
    mx = fmaxf(mx, __shfl_xor(mx, 32, 64));
    float mnew  = fmaxf(m_run, mx);
    float alpha = __expf(m_run - mnew);
    m_run = mnew;

    float sj[8];
    #pragma unroll
    for (int j = 0; j < 8; j++) {
      #pragma unroll
      for (int r = 0; r < 4; r++) sc[j][r] = __expf(sc[j][r] - mnew);
      sj[j] = (sc[j][0] + sc[j][1]) + (sc[j][2] + sc[j][3]);
    }
    float ls = ((sj[0] + sj[1]) + (sj[2] + sj[3])) + ((sj[4] + sj[5]) + (sj[6] + sj[7]));
    ls += __shfl_xor(ls, 16, 64);
    ls += __shfl_xor(ls, 32, 64);
    l_run = l_run * alpha + ls;

    // ---- P (bf16) -> per-wave LDS in [q][s] layout (b64 packed writes)
    #pragma unroll
    for (int j = 0; j < 8; j++) {
      s16x4 pk;
      pk.x = (short)f2bf(sc[j][0]); pk.y = (short)f2bf(sc[j][1]);
      pk.z = (short)f2bf(sc[j][2]); pk.w = (short)f2bf(sc[j][3]);
      *(s16x4*)&Pw[col * 136 + j * 16 + quad * 4] = pk;
    }

    // ---- rescale O by alpha of row quad*4+r (broadcast from owning lane)
    float ab[4];
    #pragma unroll
    for (int r = 0; r < 4; r++) ab[r] = __shfl(alpha, quad * 4 + r, 16);
    #pragma unroll
    for (int j = 0; j < 8; j++)
      #pragma unroll
      for (int r = 0; r < 4; r++) oacc[j][r] *= ab[r];

    // wave-private LDS: in-wave ordering only, no __syncthreads needed
    asm volatile("s_waitcnt lgkmcnt(0)" ::: "memory");
    __builtin_amdgcn_sched_barrier(0);

    // ---- O += P @ V  (P as A-operand from LDS, V^T direct from global)
    s16x8 pfrag[4];
    #pragma unroll
    for (int kk = 0; kk < 4; kk++)
      pfrag[kk] = *(const s16x8*)&Pw[col * 136 + kk * 32 + quad * 8];
    #pragma unroll
    for (int j = 0; j < 8; j++) {
      #pragma unroll
      for (int kk = 0; kk < 4; kk++) {
        s16x8 vf = *(const s16x8*)(Vh + (size_t)(j * 16 + col) * SEQ + st * 128 + kk * 32 + quad * 8);
        oacc[j] = mfma16(pfrag[kk], vf, oacc[j]);
      }
    }
  }

  // ---- finalize: 1/l broadcast per accumulator row, store bf16
  float lb[4];
  #pragma unroll
  for (int r = 0; r < 4; r++) lb[r] = 1.0f / __shfl(l_run, quad * 4 + r, 16);
  unsigned short* Oh = Ob + ((size_t)n * SEQ + (size_t)qt * 64 + w * 16) * HD;
  #pragma unroll
  for (int r = 0; r < 4; r++)
    #pragma unroll
    for (int j = 0; j < 8; j++)
      Oh[(quad * 4 + r) * HD + j * 16 + col] = f2bf(oacc[j][r] * lb[r]);
}

// ---------------------------------------------------------------------------
// Kernel 3: output projection.  (unchanged)
// ---------------------------------------------------------------------------
__global__ void __launch_bounds__(256)
oproj_kernel(const unsigned short* __restrict__ Attn,  // [16][2048][128] bf16
             const float* __restrict__ Ow,             // [2048][2048] f32
             float* __restrict__ Out)                  // [16][2048][2048] f32
{
  const int mt = blockIdx.x;
  const int nt = blockIdx.y;
  const int n  = blockIdx.z;

  __shared__ __align__(16) unsigned short Asm[128 * 40];
  __shared__ __align__(16) unsigned short Bsm[128 * 40];

  const int tid  = threadIdx.x;
  const int w    = tid >> 6;
  const int lane = tid & 63;
  const int quad = lane >> 4;
  const int col  = lane & 15;
  const int srowA = tid >> 2;
  const int schkA = tid & 3;
  const int srowB = tid >> 3;
  const int schkB = tid & 7;

  const unsigned short* A = Attn + (size_t)n * SEQ * HD + (size_t)mt * 128 * HD;
  const float* B = Ow + (size_t)nt * 128 * HIDDEN + n * HD;

  f32x4 acc[2][8];
  #pragma unroll
  for (int i = 0; i < 2; i++)
    #pragma unroll
    for (int j = 0; j < 8; j++)
      acc[i][j] = (f32x4){0.f, 0.f, 0.f, 0.f};

  for (int k0 = 0; k0 < HD; k0 += 32) {
    #pragma unroll
    for (int p = 0; p < 2; p++) {
      int r = srowA + p * 64;
      s16x8 va = *(const s16x8*)(A + (size_t)r * HD + k0 + schkA * 8);
      *(s16x8*)&Asm[r * 40 + schkA * 8] = va;
    }
    #pragma unroll
    for (int p = 0; p < 4; p++) {
      int r = srowB + p * 32;
      float4 vb = *(const float4*)(B + (size_t)r * HIDDEN + k0 + schkB * 4);
      *(s16x4*)&Bsm[r * 40 + schkB * 4] = cvt4(vb);
    }
    __syncthreads();
    s16x8 af0 = *(const s16x8*)&Asm[(w * 32 + col) * 40 + quad * 8];
    s16x8 af1 = *(const s16x8*)&Asm[(w * 32 + 16 + col) * 40 + quad * 8];
    #pragma unroll
    for (int j = 0; j < 8; j++) {
      s16x8 bf = *(const s16x8*)&Bsm[(j * 16 + col) * 40 + quad * 8];
      acc[0][j] = mfma16(af0, bf, acc[0][j]);
      acc[1][j] = mfma16(af1, bf, acc[1][j]);
    }
    __syncthreads();
  }

  float* C = Out + (size_t)n * SEQ * HIDDEN + (size_t)(mt * 128) * HIDDEN + nt * 128;
  #pragma unroll
  for (int i = 0; i < 2; i++)
    #pragma unroll
    for (int r = 0; r < 4; r++) {
      int lr = w * 32 + i * 16 + quad * 4 + r;
      #pragma unroll
      for (int j = 0; j < 8; j++)
        C[(size_t)lr * HIDDEN + j * 16 + col] = acc[i][j][r];
    }
}

// ---------------------------------------------------------------------------
extern "C" void kernel_launch(void* const* d_in, const int* in_sizes, int n_in,
                              void* d_out, int out_size, void* d_ws, size_t ws_size,
                              hipStream_t stream) {
  (void)in_sizes; (void)n_in; (void)out_size; (void)ws_size;
  const float* q_hidden = (const float*)d_in[0];
  const float* k_hidden = (const float*)d_in[1];
  const float* v_hidden = (const float*)d_in[2];
  /* d_in[3] attention_mask: causal, applied analytically */
  const int*   pos      = (const int*)d_in[4];
  const float* q_w      = (const float*)d_in[5];
  const float* k_w      = (const float*)d_in[6];
  const float* v_w      = (const float*)d_in[7];
  const float* o_w      = (const float*)d_in[8];
  float* out = (float*)d_out;

  unsigned short* Qb  = (unsigned short*)d_ws;                 // 16*2048*128 bf16
  unsigned short* Kb  = Qb  + (size_t)NH  * SEQ * HD;          // 2*2048*128
  unsigned short* Vtb = Kb  + (size_t)NKV * SEQ * HD;          // 2*128*2048
  unsigned short* Ab  = Vtb + (size_t)NKV * HD * SEQ;          // 16*2048*128

  qkv_rope_kernel<<<dim3(16, 20), 256, 0, stream>>>(q_hidden, k_hidden, v_hidden,
                                                    q_w, k_w, v_w, pos, Qb, Kb, Vtb);
  attn_kernel<<<dim3(32, 16), 256, 0, stream>>>(Qb, Kb, Vtb, Ab);
  oproj_kernel<<<dim3(16, 16, 16), 256, 0, stream>>>(Ab, o_w, out);
}

// Round 2
// 646.693 us; speedup vs baseline: 1.2645x; 1.2645x over previous
//
#include <hip/hip_runtime.h>
#include <hip/hip_bf16.h>
#include <math.h>

#define HIDDEN 2048
#define SEQ    2048
#define NH     16
#define NKV    2
#define HD     128

typedef __attribute__((ext_vector_type(8))) short s16x8;
typedef __attribute__((ext_vector_type(4))) short s16x4;
typedef __attribute__((ext_vector_type(4))) float f32x4;

__device__ __forceinline__ unsigned short f2bf(float f) {
  union { float f; unsigned int u; } v; v.f = f;
  unsigned int u = v.u;
  u += 0x7FFFu + ((u >> 16) & 1u);
  return (unsigned short)(u >> 16);
}

__device__ __forceinline__ s16x4 cvt4(float4 f) {
  s16x4 r;
  r.x = (short)f2bf(f.x); r.y = (short)f2bf(f.y);
  r.z = (short)f2bf(f.z); r.w = (short)f2bf(f.w);
  return r;
}

__device__ __forceinline__ f32x4 mfma16(s16x8 a, s16x8 b, f32x4 c) {
  return __builtin_amdgcn_mfma_f32_16x16x32_bf16(a, b, c, 0, 0, 0);
}

// async global->LDS DMA, 16B per lane, no VGPR destination
__device__ __forceinline__ void gload_lds16(const unsigned short* g, unsigned short* l) {
  __builtin_amdgcn_global_load_lds(
      (const __attribute__((address_space(1))) unsigned int*)(const void*)g,
      (__attribute__((address_space(3))) unsigned int*)(void*)l,
      16, 0, 0);
}

// ---------------------------------------------------------------------------
// Kernel 1: QKV projection + RoPE (Q,K) / transpose-store (V).  (unchanged)
// ---------------------------------------------------------------------------
__global__ void __launch_bounds__(256)
qkv_rope_kernel(const float* __restrict__ q_hidden,
                const float* __restrict__ k_hidden,
                const float* __restrict__ v_hidden,
                const float* __restrict__ q_w,
                const float* __restrict__ k_w,
                const float* __restrict__ v_w,
                const int* __restrict__ pos_ids,
                unsigned short* __restrict__ Qb,   // [16][2048][128] bf16
                unsigned short* __restrict__ Kb,   // [2][2048][128]  bf16
                unsigned short* __restrict__ Vtb)  // [2][128][2048]  bf16
{
  const int mt  = blockIdx.x;
  const int bid = blockIdx.y;

  const float* A;
  const float* B;
  int mode, head;
  if (bid < 16)      { mode = 0; head = bid;      A = q_hidden + (size_t)head*SEQ*HIDDEN; B = q_w + (size_t)head*HD*HIDDEN; }
  else if (bid < 18) { mode = 1; head = bid - 16; A = k_hidden + (size_t)head*SEQ*HIDDEN; B = k_w + (size_t)head*HD*HIDDEN; }
  else               { mode = 2; head = bid - 18; A = v_hidden + (size_t)head*SEQ*HIDDEN; B = v_w + (size_t)head*HD*HIDDEN; }

  __shared__ __align__(16) unsigned short Asm[128 * 40];
  __shared__ __align__(16) unsigned short Bsm[128 * 40];

  const int tid  = threadIdx.x;
  const int w    = tid >> 6;
  const int lane = tid & 63;
  const int quad = lane >> 4;
  const int col  = lane & 15;
  const int srow = tid >> 3;
  const int schk = tid & 7;

  f32x4 acc[2][8];
  #pragma unroll
  for (int i = 0; i < 2; i++)
    #pragma unroll
    for (int j = 0; j < 8; j++)
      acc[i][j] = (f32x4){0.f, 0.f, 0.f, 0.f};

  const int row0 = mt * 128;

  for (int k0 = 0; k0 < HIDDEN; k0 += 32) {
    #pragma unroll
    for (int p = 0; p < 4; p++) {
      int r = srow + p * 32;
      float4 va = *(const float4*)(A + (size_t)(row0 + r) * HIDDEN + k0 + schk * 4);
      float4 vb = *(const float4*)(B + (size_t)r * HIDDEN + k0 + schk * 4);
      *(s16x4*)&Asm[r * 40 + schk * 4] = cvt4(va);
      *(s16x4*)&Bsm[r * 40 + schk * 4] = cvt4(vb);
    }
    __syncthreads();
    s16x8 af0 = *(const s16x8*)&Asm[(w * 32 + col) * 40 + quad * 8];
    s16x8 af1 = *(const s16x8*)&Asm[(w * 32 + 16 + col) * 40 + quad * 8];
    #pragma unroll
    for (int j = 0; j < 8; j++) {
      s16x8 bf = *(const s16x8*)&Bsm[(j * 16 + col) * 40 + quad * 8];
      acc[0][j] = mfma16(af0, bf, acc[0][j]);
      acc[1][j] = mfma16(af1, bf, acc[1][j]);
    }
    __syncthreads();
  }

  if (mode < 2) {
    unsigned short* Cb = (mode == 0) ? (Qb + (size_t)head * SEQ * HD)
                                     : (Kb + (size_t)head * SEQ * HD);
    const float scl = (mode == 0) ? 0.08838834764831845f : 1.0f;
    float invf[4];
    #pragma unroll
    for (int j = 0; j < 4; j++)
      invf[j] = __powf(1000000.0f, -(float)(j * 16 + col) * (1.0f / 64.0f));
    #pragma unroll
    for (int i = 0; i < 2; i++) {
      #pragma unroll
      for (int r = 0; r < 4; r++) {
        int l = row0 + w * 32 + i * 16 + quad * 4 + r;
        float p = (float)pos_ids[l];
        unsigned short* crow = Cb + (size_t)l * HD;
        #pragma unroll
        for (int j = 0; j < 4; j++) {
          float ss, cc;
          sincosf(p * invf[j], &ss, &cc);
          float x1 = acc[i][j][r];
          float x2 = acc[i][j + 4][r];
          crow[j * 16 + col]       = f2bf((x1 * cc - x2 * ss) * scl);
          crow[(j + 4) * 16 + col] = f2bf((x2 * cc + x1 * ss) * scl);
        }
      }
    }
  } else {
    unsigned short* Cb = Vtb + (size_t)head * HD * SEQ;
    #pragma unroll
    for (int i = 0; i < 2; i++)
      #pragma unroll
      for (int r = 0; r < 4; r++) {
        int l = row0 + w * 32 + i * 16 + quad * 4 + r;
        #pragma unroll
        for (int j = 0; j < 8; j++) {
          int h = j * 16 + col;
          Cb[(size_t)h * SEQ + l] = f2bf(acc[i][j][r]);
        }
      }
  }
}

// ---------------------------------------------------------------------------
// Kernel 2: flash attention (causal, GQA), v3.
// Root cause of v1/v2 identical 233us: per-lane global K/V loads inside the
// MFMA loop with a register file fully consumed by acc+sc+qfrag -> every load
// serialized behind vmcnt(0). Fix: K/V staged by global_load_lds DMA (zero
// VGPR cost), K double-buffered / V single-buffered, counted vmcnt + raw
// s_barrier (never __syncthreads: it drains vmcnt). 4 waves share each tile
// (4x less L2 traffic). XOR-swizzle applied on the GLOBAL source chunk and on
// the ds_read chunk (both-sides rule) to kill the 16-way row-stride conflict.
//   QBLK=64 (16 rows/wave), KVBLK=64. LDS = 32K(K dbuf)+16K(V)+9K(P) = 57KB.
//   VGPR target <=128 -> 2 blocks/CU. Complementary qt pairing balances the
//   causal wedge (each CU's 2 resident blocks sum to 33 KV-tiles).
// ---------------------------------------------------------------------------
__global__ void __launch_bounds__(256, 2)
attn_kernel(const unsigned short* __restrict__ Qb,
            const unsigned short* __restrict__ Kb,
            const unsigned short* __restrict__ Vtb,
            unsigned short* __restrict__ Ob)   // [16][2048][128] bf16
{
  const int bx = blockIdx.x;            // 0..31
  const int n  = blockIdx.y;            // head 0..15
  const int qt = (n < 8) ? bx : (31 - bx);  // complementary pairing across CUs
  const int kv = n >> 3;

  const int tid  = threadIdx.x;
  const int w    = tid >> 6;
  const int lane = tid & 63;
  const int quad = lane >> 4;
  const int col  = lane & 15;
  const int swz  = col & 7;             // read-side XOR (row&7 == col&7 here)

  __shared__ __align__(16) unsigned short Ksm[2][64 * 128];  // 2 x 16KB
  __shared__ __align__(16) unsigned short Vsm[128 * 64];     // 16KB
  __shared__ __align__(16) unsigned short Psm[4][16 * 72];   // 9KB
  unsigned short* Pw = &Psm[w][0];

  const unsigned short* Qh = Qb  + (size_t)n  * SEQ * HD;
  const unsigned short* Kh = Kb  + (size_t)kv * SEQ * HD;
  const unsigned short* Vh = Vtb + (size_t)kv * HD * SEQ;

  const int qrow = qt * 64 + w * 16 + col;

  // ---- Q fragment (B-operand: lane&15 = q row, quad = k-chunk)
  s16x8 qfrag[4];
  #pragma unroll
  for (int kk = 0; kk < 4; kk++)
    qfrag[kk] = *(const s16x8*)(Qh + (size_t)qrow * HD + kk * 32 + quad * 8);

  // staging lane geometry (per wave: 4 passes x 1KB DMA per tile quarter)
  const int krow_l = (lane >> 4);       // K: 4 rows/pass group
  const int kch_l  = lane & 15;         // K: 16B chunk within 256B row
  const int vrow_l = (lane >> 3);       // V: 8 rows/pass group
  const int vch_l  = lane & 7;          // V: 16B chunk within 128B row

  #define STAGE_K(buf, t)                                                     \
    _Pragma("unroll")                                                         \
    for (int p = 0; p < 4; p++) {                                             \
      int row = w * 16 + p * 4 + krow_l;                                      \
      int gch = kch_l ^ (row & 7);                                            \
      gload_lds16(Kh + (size_t)((t) * 64 + row) * HD + gch * 8,               \
                  &Ksm[buf][(w * 16 + p * 4) * 128]);                         \
    }
  #define STAGE_V(t)                                                          \
    _Pragma("unroll")                                                         \
    for (int p = 0; p < 4; p++) {                                             \
      int row = w * 32 + p * 8 + vrow_l;                                      \
      int gch = vch_l ^ (row & 7);                                            \
      gload_lds16(Vh + (size_t)row * SEQ + (t) * 64 + gch * 8,                \
                  &Vsm[(w * 32 + p * 8) * 64]);                               \
    }

  f32x4 oacc[8];
  #pragma unroll
  for (int j = 0; j < 8; j++) oacc[j] = (f32x4){0.f, 0.f, 0.f, 0.f};
  float m_run = -3e38f, l_run = 0.f;

  const int nst = qt + 1;

  // ---- prologue: K[0] into buf 0
  STAGE_K(0, 0);
  asm volatile("s_waitcnt vmcnt(0)" ::: "memory");
  __builtin_amdgcn_sched_barrier(0);
  __builtin_amdgcn_s_barrier();

  for (int st = 0; st < nst; st++) {
    const int cur = st & 1;

    // issue V[st] then K[st+1] (clamped; queue = V4,K4)
    STAGE_V(st);
    const int tn = (st + 1 < nst) ? (st + 1) : st;
    STAGE_K(cur ^ 1, tn);
    __builtin_amdgcn_sched_barrier(0);

    // ---- S^T = K @ Q^T from Ksm[cur] (swizzled reads)
    f32x4 sc[4];
    #pragma unroll
    for (int j = 0; j < 4; j++) sc[j] = (f32x4){0.f, 0.f, 0.f, 0.f};
    __builtin_amdgcn_s_setprio(1);
    #pragma unroll
    for (int kk = 0; kk < 4; kk++) {
      #pragma unroll
      for (int j = 0; j < 4; j++) {
        s16x8 kf = *(const s16x8*)&Ksm[cur][(j * 16 + col) * 128 + ((kk * 4 + quad) ^ swz) * 8];
        sc[j] = mfma16(kf, qfrag[kk], sc[j]);
      }
    }
    __builtin_amdgcn_s_setprio(0);

    // ---- causal mask (only the diagonal tile)
    if (st == nst - 1) {
      #pragma unroll
      for (int j = 0; j < 4; j++)
        #pragma unroll
        for (int r = 0; r < 4; r++) {
          int sg = st * 64 + j * 16 + quad * 4 + r;
          if (sg > qrow) sc[j][r] = -1e30f;
        }
    }

    // ---- online softmax: in-lane tree over 16 vals + 2 xor-shuffles
    float mj[4];
    #pragma unroll
    for (int j = 0; j < 4; j++)
      mj[j] = fmaxf(fmaxf(sc[j][0], sc[j][1]), fmaxf(sc[j][2], sc[j][3]));
    float mx = fmaxf(fmaxf(mj[0], mj[1]), fmaxf(mj[2], mj[3]));
    mx = fmaxf(mx, __shfl_xor(mx, 16, 64));
    mx = fmaxf(mx, __shfl_xor(mx, 32, 64));
    float mnew  = fmaxf(m_run, mx);
    float alpha = __expf(m_run - mnew);
    m_run = mnew;

    float ls = 0.f;
    #pragma unroll
    for (int j = 0; j < 4; j++) {
      #pragma unroll
      for (int r = 0; r < 4; r++) sc[j][r] = __expf(sc[j][r] - mnew);
      ls += (sc[j][0] + sc[j][1]) + (sc[j][2] + sc[j][3]);
    }
    ls += __shfl_xor(ls, 16, 64);
    ls += __shfl_xor(ls, 32, 64);
    l_run = l_run * alpha + ls;

    // ---- P (bf16) -> per-wave LDS in [q][s] layout
    #pragma unroll
    for (int j = 0; j < 4; j++) {
      s16x4 pk;
      pk.x = (short)f2bf(sc[j][0]); pk.y = (short)f2bf(sc[j][1]);
      pk.z = (short)f2bf(sc[j][2]); pk.w = (short)f2bf(sc[j][3]);
      *(s16x4*)&Pw[col * 72 + j * 16 + quad * 4] = pk;
    }

    // ---- rescale O
    float ab[4];
    #pragma unroll
    for (int r = 0; r < 4; r++) ab[r] = __shfl(alpha, quad * 4 + r, 16);
    #pragma unroll
    for (int j = 0; j < 8; j++)
      #pragma unroll
      for (int r = 0; r < 4; r++) oacc[j][r] *= ab[r];

    // V[st] landed (K[st+1] stays in flight); P writes visible to self
    asm volatile("s_waitcnt vmcnt(4) lgkmcnt(0)" ::: "memory");
    __builtin_amdgcn_sched_barrier(0);
    __builtin_amdgcn_s_barrier();
    __builtin_amdgcn_sched_barrier(0);

    // ---- O += P @ V from LDS
    s16x8 pfrag[2];
    #pragma unroll
    for (int kk = 0; kk < 2; kk++)
      pfrag[kk] = *(const s16x8*)&Pw[col * 72 + kk * 32 + quad * 8];
    __builtin_amdgcn_s_setprio(1);
    #pragma unroll
    for (int j = 0; j < 8; j++) {
      #pragma unroll
      for (int kk = 0; kk < 2; kk++) {
        s16x8 vf = *(const s16x8*)&Vsm[(j * 16 + col) * 64 + ((kk * 4 + quad) ^ swz) * 8];
        oacc[j] = mfma16(pfrag[kk], vf, oacc[j]);
      }
    }
    __builtin_amdgcn_s_setprio(0);

    // drain K[st+1]; all waves past PV before next V/K overwrite
    asm volatile("s_waitcnt vmcnt(0)" ::: "memory");
    __builtin_amdgcn_sched_barrier(0);
    __builtin_amdgcn_s_barrier();
    __builtin_amdgcn_sched_barrier(0);
  }

  // ---- finalize
  float lb[4];
  #pragma unroll
  for (int r = 0; r < 4; r++) lb[r] = 1.0f / __shfl(l_run, quad * 4 + r, 16);
  unsigned short* Oh = Ob + ((size_t)n * SEQ + (size_t)qt * 64 + w * 16) * HD;
  #pragma unroll
  for (int r = 0; r < 4; r++)
    #pragma unroll
    for (int j = 0; j < 8; j++)
      Oh[(quad * 4 + r) * HD + j * 16 + col] = f2bf(oacc[j][r] * lb[r]);
  #undef STAGE_K
  #undef STAGE_V
}

// ---------------------------------------------------------------------------
// Kernel 3: output projection.  (unchanged)
// ---------------------------------------------------------------------------
__global__ void __launch_bounds__(256)
oproj_kernel(const unsigned short* __restrict__ Attn,  // [16][2048][128] bf16
             const float* __restrict__ Ow,             // [2048][2048] f32
             float* __restrict__ Out)                  // [16][2048][2048] f32
{
  const int mt = blockIdx.x;
  const int nt = blockIdx.y;
  const int n  = blockIdx.z;

  __shared__ __align__(16) unsigned short Asm[128 * 40];
  __shared__ __align__(16) unsigned short Bsm[128 * 40];

  const int tid  = threadIdx.x;
  const int w    = tid >> 6;
  const int lane = tid & 63;
  const int quad = lane >> 4;
  const int col  = lane & 15;
  const int srowA = tid >> 2;
  const int schkA = tid & 3;
  const int srowB = tid >> 3;
  const int schkB = tid & 7;

  const unsigned short* A = Attn + (size_t)n * SEQ * HD + (size_t)mt * 128 * HD;
  const float* B = Ow + (size_t)nt * 128 * HIDDEN + n * HD;

  f32x4 acc[2][8];
  #pragma unroll
  for (int i = 0; i < 2; i++)
    #pragma unroll
    for (int j = 0; j < 8; j++)
      acc[i][j] = (f32x4){0.f, 0.f, 0.f, 0.f};

  for (int k0 = 0; k0 < HD; k0 += 32) {
    #pragma unroll
    for (int p = 0; p < 2; p++) {
      int r = srowA + p * 64;
      s16x8 va = *(const s16x8*)(A + (size_t)r * HD + k0 + schkA * 8);
      *(s16x8*)&Asm[r * 40 + schkA * 8] = va;
    }
    #pragma unroll
    for (int p = 0; p < 4; p++) {
      int r = srowB + p * 32;
      float4 vb = *(const float4*)(B + (size_t)r * HIDDEN + k0 + schkB * 4);
      *(s16x4*)&Bsm[r * 40 + schkB * 4] = cvt4(vb);
    }
    __syncthreads();
    s16x8 af0 = *(const s16x8*)&Asm[(w * 32 + col) * 40 + quad * 8];
    s16x8 af1 = *(const s16x8*)&Asm[(w * 32 + 16 + col) * 40 + quad * 8];
    #pragma unroll
    for (int j = 0; j < 8; j++) {
      s16x8 bf = *(const s16x8*)&Bsm[(j * 16 + col) * 40 + quad * 8];
      acc[0][j] = mfma16(af0, bf, acc[0][j]);
      acc[1][j] = mfma16(af1, bf, acc[1][j]);
    }
    __syncthreads();
  }

  float* C = Out + (size_t)n * SEQ * HIDDEN + (size_t)(mt * 128) * HIDDEN + nt * 128;
  #pragma unroll
  for (int i = 0; i < 2; i++)
    #pragma unroll
    for (int r = 0; r < 4; r++) {
      int lr = w * 32 + i * 16 + quad * 4 + r;
      #pragma unroll
      for (int j = 0; j < 8; j++)
        C[(size_t)lr * HIDDEN + j * 16 + col] = acc[i][j][r];
    }
}

// ---------------------------------------------------------------------------
extern "C" void kernel_launch(void* const* d_in, const int* in_sizes, int n_in,
                              void* d_out, int out_size, void* d_ws, size_t ws_size,
                              hipStream_t stream) {
  (void)in_sizes; (void)n_in; (void)out_size; (void)ws_size;
  const float* q_hidden = (const float*)d_in[0];
  const float* k_hidden = (const float*)d_in[1];
  const float* v_hidden = (const float*)d_in[2];
  /* d_in[3] attention_mask: causal, applied analytically */
  const int*   pos      = (const int*)d_in[4];
  const float* q_w      = (const float*)d_in[5];
  const float* k_w      = (const float*)d_in[6];
  const float* v_w      = (const float*)d_in[7];
  const float* o_w      = (const float*)d_in[8];
  float* out = (float*)d_out;

  unsigned short* Qb  = (unsigned short*)d_ws;                 // 16*2048*128 bf16
  unsigned short* Kb  = Qb  + (size_t)NH  * SEQ * HD;          // 2*2048*128
  unsigned short* Vtb = Kb  + (size_t)NKV * SEQ * HD;          // 2*128*2048
  unsigned short* Ab  = Vtb + (size_t)NKV * HD * SEQ;          // 16*2048*128

  qkv_rope_kernel<<<dim3(16, 20), 256, 0, stream>>>(q_hidden, k_hidden, v_hidden,
                                                    q_w, k_w, v_w, pos, Qb, Kb, Vtb);
  attn_kernel<<<dim3(32, 16), 256, 0, stream>>>(Qb, Kb, Vtb, Ab);
  oproj_kernel<<<dim3(16, 16, 16), 256, 0, stream>>>(Ab, o_w, out);
}

// Round 3
// 636.534 us; speedup vs baseline: 1.2847x; 1.0160x over previous
//
#include <hip/hip_runtime.h>
#include <hip/hip_bf16.h>
#include <math.h>

#define HIDDEN 2048
#define SEQ    2048
#define NH     16
#define NKV    2
#define HD     128

typedef __attribute__((ext_vector_type(8))) short s16x8;
typedef __attribute__((ext_vector_type(4))) short s16x4;
typedef __attribute__((ext_vector_type(4))) float f32x4;

__device__ __forceinline__ unsigned short f2bf(float f) {
  union { float f; unsigned int u; } v; v.f = f;
  unsigned int u = v.u;
  u += 0x7FFFu + ((u >> 16) & 1u);
  return (unsigned short)(u >> 16);
}

// packed f32x2 -> bf16x2 (RNE, matches f2bf), 1 instr per 2 elems
__device__ __forceinline__ unsigned int cvtpk2(float lo, float hi) {
  unsigned int r;
  asm("v_cvt_pk_bf16_f32 %0, %1, %2" : "=v"(r) : "v"(lo), "v"(hi));
  return r;
}

__device__ __forceinline__ s16x4 cvt4(float4 f) {
  union { s16x4 v; unsigned int u[2]; } r;
  r.u[0] = cvtpk2(f.x, f.y);
  r.u[1] = cvtpk2(f.z, f.w);
  return r.v;
}

__device__ __forceinline__ f32x4 mfma16(s16x8 a, s16x8 b, f32x4 c) {
  return __builtin_amdgcn_mfma_f32_16x16x32_bf16(a, b, c, 0, 0, 0);
}

// async global->LDS DMA, 16B per lane, no VGPR destination
__device__ __forceinline__ void gload_lds16(const unsigned short* g, unsigned short* l) {
  __builtin_amdgcn_global_load_lds(
      (const __attribute__((address_space(1))) unsigned int*)(const void*)g,
      (__attribute__((address_space(3))) unsigned int*)(void*)l,
      16, 0, 0);
}

// ---------------------------------------------------------------------------
// Kernel 1: QKV projection + RoPE (Q,K) / transpose-store (V), v2.
// v1 cost: per K-step {load -> slow int-op f2bf cvt -> write -> __syncthreads
// (drains vmcnt) -> MFMA -> __syncthreads} with ~1 block/CU -> full HBM
// latency exposed every step. v2: double-buffered LDS, register prefetch of
// tile t+2 issued under compute of tile t, cvt via v_cvt_pk_bf16_f32, raw
// s_barrier + lgkmcnt(0) (vmcnt NOT drained -> prefetch stays in flight).
// ---------------------------------------------------------------------------
__global__ void __launch_bounds__(256)
qkv_rope_kernel(const float* __restrict__ q_hidden,
                const float* __restrict__ k_hidden,
                const float* __restrict__ v_hidden,
                const float* __restrict__ q_w,
                const float* __restrict__ k_w,
                const float* __restrict__ v_w,
                const int* __restrict__ pos_ids,
                unsigned short* __restrict__ Qb,   // [16][2048][128] bf16
                unsigned short* __restrict__ Kb,   // [2][2048][128]  bf16
                unsigned short* __restrict__ Vtb)  // [2][128][2048]  bf16
{
  const int mt  = blockIdx.x;
  const int bid = blockIdx.y;

  const float* A;
  const float* B;
  int mode, head;
  if (bid < 16)      { mode = 0; head = bid;      A = q_hidden + (size_t)head*SEQ*HIDDEN; B = q_w + (size_t)head*HD*HIDDEN; }
  else if (bid < 18) { mode = 1; head = bid - 16; A = k_hidden + (size_t)head*SEQ*HIDDEN; B = k_w + (size_t)head*HD*HIDDEN; }
  else               { mode = 2; head = bid - 18; A = v_hidden + (size_t)head*SEQ*HIDDEN; B = v_w + (size_t)head*HD*HIDDEN; }

  __shared__ __align__(16) unsigned short Asm[2][128 * 40];
  __shared__ __align__(16) unsigned short Bsm[2][128 * 40];

  const int tid  = threadIdx.x;
  const int w    = tid >> 6;
  const int lane = tid & 63;
  const int quad = lane >> 4;
  const int col  = lane & 15;
  const int srow = tid >> 3;   // 0..31
  const int schk = tid & 7;    // 0..7

  f32x4 acc[2][8];
  #pragma unroll
  for (int i = 0; i < 2; i++)
    #pragma unroll
    for (int j = 0; j < 8; j++)
      acc[i][j] = (f32x4){0.f, 0.f, 0.f, 0.f};

  const int row0 = mt * 128;

  float4 pa[4], pb[4];
  #define LOADT(k0)                                                           \
    _Pragma("unroll")                                                         \
    for (int p = 0; p < 4; p++) {                                             \
      int r = srow + p * 32;                                                  \
      pa[p] = *(const float4*)(A + (size_t)(row0 + r) * HIDDEN + (k0) + schk * 4); \
      pb[p] = *(const float4*)(B + (size_t)r * HIDDEN + (k0) + schk * 4);     \
    }
  #define WRITET(bi)                                                          \
    _Pragma("unroll")                                                         \
    for (int p = 0; p < 4; p++) {                                             \
      int r = srow + p * 32;                                                  \
      *(s16x4*)&Asm[bi][r * 40 + schk * 4] = cvt4(pa[p]);                     \
      *(s16x4*)&Bsm[bi][r * 40 + schk * 4] = cvt4(pb[p]);                     \
    }

  // prologue: tile0 -> buf0; tile1 loads in flight
  LOADT(0);
  WRITET(0);
  LOADT(32);
  asm volatile("s_waitcnt lgkmcnt(0)" ::: "memory");
  __builtin_amdgcn_sched_barrier(0);
  __builtin_amdgcn_s_barrier();

  for (int t = 0; t < 64; t++) {
    const int cur = t & 1;
    // write tile t+1 (regs; compiler inserts exact vmcnt wait), issue t+2
    if (t < 63) { WRITET(cur ^ 1); }
    if (t < 62) { LOADT((t + 2) * 32); }
    __builtin_amdgcn_sched_barrier(0);

    s16x8 af0 = *(const s16x8*)&Asm[cur][(w * 32 + col) * 40 + quad * 8];
    s16x8 af1 = *(const s16x8*)&Asm[cur][(w * 32 + 16 + col) * 40 + quad * 8];
    #pragma unroll
    for (int j = 0; j < 8; j++) {
      s16x8 bf = *(const s16x8*)&Bsm[cur][(j * 16 + col) * 40 + quad * 8];
      acc[0][j] = mfma16(af0, bf, acc[0][j]);
      acc[1][j] = mfma16(af1, bf, acc[1][j]);
    }
    // my ds_writes + ds_reads retired; raw barrier keeps t+2 loads in flight
    asm volatile("s_waitcnt lgkmcnt(0)" ::: "memory");
    __builtin_amdgcn_sched_barrier(0);
    __builtin_amdgcn_s_barrier();
  }
  #undef LOADT
  #undef WRITET

  if (mode < 2) {
    unsigned short* Cb = (mode == 0) ? (Qb + (size_t)head * SEQ * HD)
                                     : (Kb + (size_t)head * SEQ * HD);
    const float scl = (mode == 0) ? 0.08838834764831845f : 1.0f;
    float invf[4];
    #pragma unroll
    for (int j = 0; j < 4; j++)
      invf[j] = __powf(1000000.0f, -(float)(j * 16 + col) * (1.0f / 64.0f));
    #pragma unroll
    for (int i = 0; i < 2; i++) {
      #pragma unroll
      for (int r = 0; r < 4; r++) {
        int l = row0 + w * 32 + i * 16 + quad * 4 + r;
        float p = (float)pos_ids[l];
        unsigned short* crow = Cb + (size_t)l * HD;
        #pragma unroll
        for (int j = 0; j < 4; j++) {
          float ss, cc;
          sincosf(p * invf[j], &ss, &cc);
          float x1 = acc[i][j][r];
          float x2 = acc[i][j + 4][r];
          crow[j * 16 + col]       = f2bf((x1 * cc - x2 * ss) * scl);
          crow[(j + 4) * 16 + col] = f2bf((x2 * cc + x1 * ss) * scl);
        }
      }
    }
  } else {
    unsigned short* Cb = Vtb + (size_t)head * HD * SEQ;
    #pragma unroll
    for (int i = 0; i < 2; i++)
      #pragma unroll
      for (int r = 0; r < 4; r++) {
        int l = row0 + w * 32 + i * 16 + quad * 4 + r;
        #pragma unroll
        for (int j = 0; j < 8; j++) {
          int h = j * 16 + col;
          Cb[(size_t)h * SEQ + l] = f2bf(acc[i][j][r]);
        }
      }
  }
}

// ---------------------------------------------------------------------------
// Kernel 2: flash attention (causal, GQA), v3.  (unchanged from round 2)
// ---------------------------------------------------------------------------
__global__ void __launch_bounds__(256, 2)
attn_kernel(const unsigned short* __restrict__ Qb,
            const unsigned short* __restrict__ Kb,
            const unsigned short* __restrict__ Vtb,
            unsigned short* __restrict__ Ob)   // [16][2048][128] bf16
{
  const int bx = blockIdx.x;            // 0..31
  const int n  = blockIdx.y;            // head 0..15
  const int qt = (n < 8) ? bx : (31 - bx);  // complementary pairing across CUs
  const int kv = n >> 3;

  const int tid  = threadIdx.x;
  const int w    = tid >> 6;
  const int lane = tid & 63;
  const int quad = lane >> 4;
  const int col  = lane & 15;
  const int swz  = col & 7;

  __shared__ __align__(16) unsigned short Ksm[2][64 * 128];  // 2 x 16KB
  __shared__ __align__(16) unsigned short Vsm[128 * 64];     // 16KB
  __shared__ __align__(16) unsigned short Psm[4][16 * 72];   // 9KB
  unsigned short* Pw = &Psm[w][0];

  const unsigned short* Qh = Qb  + (size_t)n  * SEQ * HD;
  const unsigned short* Kh = Kb  + (size_t)kv * SEQ * HD;
  const unsigned short* Vh = Vtb + (size_t)kv * HD * SEQ;

  const int qrow = qt * 64 + w * 16 + col;

  s16x8 qfrag[4];
  #pragma unroll
  for (int kk = 0; kk < 4; kk++)
    qfrag[kk] = *(const s16x8*)(Qh + (size_t)qrow * HD + kk * 32 + quad * 8);

  const int krow_l = (lane >> 4);
  const int kch_l  = lane & 15;
  const int vrow_l = (lane >> 3);
  const int vch_l  = lane & 7;

  #define STAGE_K(buf, t)                                                     \
    _Pragma("unroll")                                                         \
    for (int p = 0; p < 4; p++) {                                             \
      int row = w * 16 + p * 4 + krow_l;                                      \
      int gch = kch_l ^ (row & 7);                                            \
      gload_lds16(Kh + (size_t)((t) * 64 + row) * HD + gch * 8,               \
                  &Ksm[buf][(w * 16 + p * 4) * 128]);                         \
    }
  #define STAGE_V(t)                                                          \
    _Pragma("unroll")                                                         \
    for (int p = 0; p < 4; p++) {                                             \
      int row = w * 32 + p * 8 + vrow_l;                                      \
      int gch = vch_l ^ (row & 7);                                            \
      gload_lds16(Vh + (size_t)row * SEQ + (t) * 64 + gch * 8,                \
                  &Vsm[(w * 32 + p * 8) * 64]);                               \
    }

  f32x4 oacc[8];
  #pragma unroll
  for (int j = 0; j < 8; j++) oacc[j] = (f32x4){0.f, 0.f, 0.f, 0.f};
  float m_run = -3e38f, l_run = 0.f;

  const int nst = qt + 1;

  STAGE_K(0, 0);
  asm volatile("s_waitcnt vmcnt(0)" ::: "memory");
  __builtin_amdgcn_sched_barrier(0);
  __builtin_amdgcn_s_barrier();

  for (int st = 0; st < nst; st++) {
    const int cur = st & 1;

    STAGE_V(st);
    const int tn = (st + 1 < nst) ? (st + 1) : st;
    STAGE_K(cur ^ 1, tn);
    __builtin_amdgcn_sched_barrier(0);

    f32x4 sc[4];
    #pragma unroll
    for (int j = 0; j < 4; j++) sc[j] = (f32x4){0.f, 0.f, 0.f, 0.f};
    __builtin_amdgcn_s_setprio(1);
    #pragma unroll
    for (int kk = 0; kk < 4; kk++) {
      #pragma unroll
      for (int j = 0; j < 4; j++) {
        s16x8 kf = *(const s16x8*)&Ksm[cur][(j * 16 + col) * 128 + ((kk * 4 + quad) ^ swz) * 8];
        sc[j] = mfma16(kf, qfrag[kk], sc[j]);
      }
    }
    __builtin_amdgcn_s_setprio(0);

    if (st == nst - 1) {
      #pragma unroll
      for (int j = 0; j < 4; j++)
        #pragma unroll
        for (int r = 0; r < 4; r++) {
          int sg = st * 64 + j * 16 + quad * 4 + r;
          if (sg > qrow) sc[j][r] = -1e30f;
        }
    }

    float mj[4];
    #pragma unroll
    for (int j = 0; j < 4; j++)
      mj[j] = fmaxf(fmaxf(sc[j][0], sc[j][1]), fmaxf(sc[j][2], sc[j][3]));
    float mx = fmaxf(fmaxf(mj[0], mj[1]), fmaxf(mj[2], mj[3]));
    mx = fmaxf(mx, __shfl_xor(mx, 16, 64));
    mx = fmaxf(mx, __shfl_xor(mx, 32, 64));
    float mnew  = fmaxf(m_run, mx);
    float alpha = __expf(m_run - mnew);
    m_run = mnew;

    float ls = 0.f;
    #pragma unroll
    for (int j = 0; j < 4; j++) {
      #pragma unroll
      for (int r = 0; r < 4; r++) sc[j][r] = __expf(sc[j][r] - mnew);
      ls += (sc[j][0] + sc[j][1]) + (sc[j][2] + sc[j][3]);
    }
    ls += __shfl_xor(ls, 16, 64);
    ls += __shfl_xor(ls, 32, 64);
    l_run = l_run * alpha + ls;

    #pragma unroll
    for (int j = 0; j < 4; j++) {
      s16x4 pk;
      pk.x = (short)f2bf(sc[j][0]); pk.y = (short)f2bf(sc[j][1]);
      pk.z = (short)f2bf(sc[j][2]); pk.w = (short)f2bf(sc[j][3]);
      *(s16x4*)&Pw[col * 72 + j * 16 + quad * 4] = pk;
    }

    float ab[4];
    #pragma unroll
    for (int r = 0; r < 4; r++) ab[r] = __shfl(alpha, quad * 4 + r, 16);
    #pragma unroll
    for (int j = 0; j < 8; j++)
      #pragma unroll
      for (int r = 0; r < 4; r++) oacc[j][r] *= ab[r];

    asm volatile("s_waitcnt vmcnt(4) lgkmcnt(0)" ::: "memory");
    __builtin_amdgcn_sched_barrier(0);
    __builtin_amdgcn_s_barrier();
    __builtin_amdgcn_sched_barrier(0);

    s16x8 pfrag[2];
    #pragma unroll
    for (int kk = 0; kk < 2; kk++)
      pfrag[kk] = *(const s16x8*)&Pw[col * 72 + kk * 32 + quad * 8];
    __builtin_amdgcn_s_setprio(1);
    #pragma unroll
    for (int j = 0; j < 8; j++) {
      #pragma unroll
      for (int kk = 0; kk < 2; kk++) {
        s16x8 vf = *(const s16x8*)&Vsm[(j * 16 + col) * 64 + ((kk * 4 + quad) ^ swz) * 8];
        oacc[j] = mfma16(pfrag[kk], vf, oacc[j]);
      }
    }
    __builtin_amdgcn_s_setprio(0);

    asm volatile("s_waitcnt vmcnt(0)" ::: "memory");
    __builtin_amdgcn_sched_barrier(0);
    __builtin_amdgcn_s_barrier();
    __builtin_amdgcn_sched_barrier(0);
  }

  float lb[4];
  #pragma unroll
  for (int r = 0; r < 4; r++) lb[r] = 1.0f / __shfl(l_run, quad * 4 + r, 16);
  unsigned short* Oh = Ob + ((size_t)n * SEQ + (size_t)qt * 64 + w * 16) * HD;
  #pragma unroll
  for (int r = 0; r < 4; r++)
    #pragma unroll
    for (int j = 0; j < 8; j++)
      Oh[(quad * 4 + r) * HD + j * 16 + col] = f2bf(oacc[j][r] * lb[r]);
  #undef STAGE_K
  #undef STAGE_V
}

// ---------------------------------------------------------------------------
// Kernel 3: output projection, v2 — persistent blocks.
// v1: 4096 tiny blocks (16/CU serial), 2 barriers per 4-step K-loop, B
// re-staged+converted 16x. v2: grid (16 nt,16 n) = 256 blocks = 1/CU.
// B (128x128) staged once; A double-buffered in LDS with reg prefetch across
// raw barriers; k-loop barrier-free; stores fire-and-forget (vmcnt never
// drained in the loop) -> rides the 268 MB HBM-write roofline (~45 us).
// ---------------------------------------------------------------------------
__global__ void __launch_bounds__(256)
oproj_kernel(const unsigned short* __restrict__ Attn,  // [16][2048][128] bf16
             const float* __restrict__ Ow,             // [2048][2048] f32
             float* __restrict__ Out)                  // [16][2048][2048] f32
{
  const int nt = blockIdx.x;  // 0..15 output-col tile
  const int n  = blockIdx.y;  // 0..15 head

  __shared__ __align__(16) unsigned short Bsm[128 * 136];     // 34.8 KB
  __shared__ __align__(16) unsigned short Asm[2][128 * 136];  // 69.6 KB

  const int tid  = threadIdx.x;
  const int w    = tid >> 6;
  const int lane = tid & 63;
  const int quad = lane >> 4;
  const int col  = lane & 15;

  const unsigned short* Ah = Attn + (size_t)n * SEQ * HD;
  const float* Bw = Ow + (size_t)nt * 128 * HIDDEN + n * HD;  // row d: Ow[d][n*128+h]

  // ---- stage B once: Bsm[d][h], d=0..127 (out cols), h=0..127 (K)
  {
    const int r0 = tid >> 3;   // 0..31
    const int ck = tid & 7;    // 0..7 (4-float chunks)
    #pragma unroll
    for (int q = 0; q < 4; q++)
      #pragma unroll
      for (int p = 0; p < 4; p++) {
        int r = r0 + p * 32;
        float4 vb = *(const float4*)(Bw + (size_t)r * HIDDEN + q * 32 + ck * 4);
        *(s16x4*)&Bsm[r * 136 + q * 32 + ck * 4] = cvt4(vb);
      }
  }

  // ---- A staging: reg-prefetched double buffer
  const int ar = tid >> 1;     // row 0..127
  const int ah = tid & 1;      // half-row (64 elems)
  s16x8 areg[8];
  #define LOADA(mt_)                                                          \
    _Pragma("unroll")                                                         \
    for (int c = 0; c < 8; c++)                                               \
      areg[c] = *(const s16x8*)(Ah + (size_t)((mt_) * 128 + ar) * HD + ah * 64 + c * 8);
  #define WRITEA(bi)                                                          \
    _Pragma("unroll")                                                         \
    for (int c = 0; c < 8; c++)                                               \
      *(s16x8*)&Asm[bi][ar * 136 + ah * 64 + c * 8] = areg[c];

  LOADA(0);
  WRITEA(0);
  LOADA(1);
  __syncthreads();   // prologue only (drains vmcnt once — acceptable)

  for (int mt = 0; mt < 16; mt++) {
    const int cur = mt & 1;

    // write tile mt+1 (compiler waits its vmcnt), issue mt+2 loads
    if (mt < 15) { WRITEA(cur ^ 1); }
    if (mt < 14) { LOADA(mt + 2); }
    __builtin_amdgcn_sched_barrier(0);

    f32x4 acc[2][8];
    #pragma unroll
    for (int i = 0; i < 2; i++)
      #pragma unroll
      for (int j = 0; j < 8; j++)
        acc[i][j] = (f32x4){0.f, 0.f, 0.f, 0.f};

    #pragma unroll
    for (int k0 = 0; k0 < HD; k0 += 32) {
      s16x8 af0 = *(const s16x8*)&Asm[cur][(w * 32 + col) * 136 + k0 + quad * 8];
      s16x8 af1 = *(const s16x8*)&Asm[cur][(w * 32 + 16 + col) * 136 + k0 + quad * 8];
      #pragma unroll
      for (int j = 0; j < 8; j++) {
        s16x8 bf = *(const s16x8*)&Bsm[(j * 16 + col) * 136 + k0 + quad * 8];
        acc[0][j] = mfma16(af0, bf, acc[0][j]);
        acc[1][j] = mfma16(af1, bf, acc[1][j]);
      }
    }

    // epilogue: fire-and-forget stores (never drained in-loop)
    float* C = Out + (size_t)n * SEQ * HIDDEN + (size_t)(mt * 128) * HIDDEN + nt * 128;
    #pragma unroll
    for (int i = 0; i < 2; i++)
      #pragma unroll
      for (int r = 0; r < 4; r++) {
        int lr = w * 32 + i * 16 + quad * 4 + r;
        #pragma unroll
        for (int j = 0; j < 8; j++)
          C[(size_t)lr * HIDDEN + j * 16 + col] = acc[i][j][r];
      }

    // ds_writes visible + my ds_reads retired before others overwrite
    asm volatile("s_waitcnt lgkmcnt(0)" ::: "memory");
    __builtin_amdgcn_sched_barrier(0);
    __builtin_amdgcn_s_barrier();
  }
  #undef LOADA
  #undef WRITEA
}

// ---------------------------------------------------------------------------
extern "C" void kernel_launch(void* const* d_in, const int* in_sizes, int n_in,
                              void* d_out, int out_size, void* d_ws, size_t ws_size,
                              hipStream_t stream) {
  (void)in_sizes; (void)n_in; (void)out_size; (void)ws_size;
  const float* q_hidden = (const float*)d_in[0];
  const float* k_hidden = (const float*)d_in[1];
  const float* v_hidden = (const float*)d_in[2];
  /* d_in[3] attention_mask: causal, applied analytically */
  const int*   pos      = (const int*)d_in[4];
  const float* q_w      = (const float*)d_in[5];
  const float* k_w      = (const float*)d_in[6];
  const float* v_w      = (const float*)d_in[7];
  const float* o_w      = (const float*)d_in[8];
  float* out = (float*)d_out;

  unsigned short* Qb  = (unsigned short*)d_ws;                 // 16*2048*128 bf16
  unsigned short* Kb  = Qb  + (size_t)NH  * SEQ * HD;          // 2*2048*128
  unsigned short* Vtb = Kb  + (size_t)NKV * SEQ * HD;          // 2*128*2048
  unsigned short* Ab  = Vtb + (size_t)NKV * HD * SEQ;          // 16*2048*128

  qkv_rope_kernel<<<dim3(16, 20), 256, 0, stream>>>(q_hidden, k_hidden, v_hidden,
                                                    q_w, k_w, v_w, pos, Qb, Kb, Vtb);
  attn_kernel<<<dim3(32, 16), 256, 0, stream>>>(Qb, Kb, Vtb, Ab);
  oproj_kernel<<<dim3(16, 16), 256, 0, stream>>>(Ab, o_w, out);
}